// Round 1
// baseline (1335.505 us; speedup 1.0000x reference)
//
#include <hip/hip_runtime.h>

#define HW 256
#define HWHW 65536
#define TOTAL 19296

// ---------------- MLP: x_meta[16,16] -> h0[16,256] (LDS) -> h1[16,512] (ws) ----------------
__global__ __launch_bounds__(512) void mlp_kernel(
    const float* __restrict__ x_meta, const float* __restrict__ w0, const float* __restrict__ b0,
    const float* __restrict__ w1, const float* __restrict__ b1, float* __restrict__ h1)
{
    __shared__ float xm[16 * 16];
    __shared__ float h0s[16 * 256];
    int t = threadIdx.x;
    if (t < 256) xm[t] = x_meta[t];
    __syncthreads();
    if (t < 256) {
        int j = t;
        float acc[16];
        float bj = b0[j];
#pragma unroll
        for (int b = 0; b < 16; ++b) acc[b] = bj;
#pragma unroll
        for (int i = 0; i < 16; ++i) {
            float w = w0[i * 256 + j];
#pragma unroll
            for (int b = 0; b < 16; ++b) acc[b] += xm[b * 16 + i] * w;
        }
#pragma unroll
        for (int b = 0; b < 16; ++b) h0s[b * 256 + j] = fmaxf(acc[b], 0.f);
    }
    __syncthreads();
    {
        int j = t;  // 0..511
        float acc[16];
        float bj = b1[j];
#pragma unroll
        for (int b = 0; b < 16; ++b) acc[b] = bj;
        for (int k = 0; k < 256; ++k) {
            float w = w1[k * 512 + j];
#pragma unroll
            for (int b = 0; b < 16; ++b) acc[b] += h0s[b * 256 + k] * w;
        }
#pragma unroll
        for (int b = 0; b < 16; ++b) h1[b * 512 + j] = fmaxf(acc[b], 0.f);
    }
}

// ---------------- flat[16,19296] = relu(h1 @ w2 + b2); w2 is [512,19296] ----------------
__global__ __launch_bounds__(128) void flat_kernel(
    const float* __restrict__ h1, const float* __restrict__ w2, const float* __restrict__ b2,
    float* __restrict__ flat)
{
    __shared__ float h1s[16 * 512];
    int t = threadIdx.x;
    for (int idx = t; idx < 16 * 512; idx += 128) h1s[idx] = h1[idx];
    __syncthreads();
    int j = blockIdx.x * 128 + t;
    if (j >= TOTAL) return;
    float acc[16];
    float bj = b2[j];
#pragma unroll
    for (int b = 0; b < 16; ++b) acc[b] = bj;
    const float* w2j = w2 + j;
    for (int k = 0; k < 512; k += 4) {
        float wv0 = w2j[(size_t)(k + 0) * TOTAL];
        float wv1 = w2j[(size_t)(k + 1) * TOTAL];
        float wv2 = w2j[(size_t)(k + 2) * TOTAL];
        float wv3 = w2j[(size_t)(k + 3) * TOTAL];
#pragma unroll
        for (int b = 0; b < 16; ++b) {
            const float4 h4 = *(const float4*)&h1s[b * 512 + k];
            acc[b] += h4.x * wv0 + h4.y * wv1 + h4.z * wv2 + h4.w * wv3;
        }
    }
#pragma unroll
    for (int b = 0; b < 16; ++b) flat[(size_t)b * TOTAL + j] = fmaxf(acc[b], 0.f);
}

// ---------------- conv0: x[b,1,H,W] -> out0[bb,32,H,W]; ker[b,oc] = flat[b, oc*9 .. +9] ----------------
__global__ __launch_bounds__(256) void conv0_kernel(
    const float* __restrict__ x, const float* __restrict__ flat,
    float* __restrict__ out0, int b0off)
{
    int xcol = threadIdx.x;
    int y = blockIdx.x;
    int oc = blockIdx.y;
    int bb = blockIdx.z;
    int b = b0off + bb;
    const float* wsrc = flat + (size_t)b * TOTAL + oc * 9;
    float w[9];
#pragma unroll
    for (int k = 0; k < 9; ++k) w[k] = wsrc[k];
    const float* xin = x + (size_t)b * HWHW;
    float acc = 0.f;
#pragma unroll
    for (int ky = 0; ky < 3; ++ky) {
        int gy = y + ky - 1;
        if (gy < 0 || gy >= HW) continue;
#pragma unroll
        for (int kx = 0; kx < 3; ++kx) {
            int gx = xcol + kx - 1;
            if (gx < 0 || gx >= HW) continue;
            acc += xin[gy * HW + gx] * w[ky * 3 + kx];
        }
    }
    out0[((size_t)(bb * 32 + oc)) * HWHW + y * HW + xcol] = acc;
}

// ---------------- conv1: out0[bb,32,H,W] -> out1[bb,64,H,W] ----------------
// ker[b,oc,ic] = flat[b, 288 + oc*288 + ic*9 .. +9]
// block: 256 threads = 32x8, each thread 4 vertical pixels; 4 oc per block; tile 32x32.
__global__ __launch_bounds__(256) void conv1_kernel(
    const float* __restrict__ out0, const float* __restrict__ flat,
    float* __restrict__ out1, int b0off)
{
    __shared__ float wsm[4 * 288];
    __shared__ float tile[34 * 34];
    int t = threadIdx.x;
    int tileid = blockIdx.x;  // 0..63
    int ocg = blockIdx.y;     // 0..15
    int bb = blockIdx.z;
    int b = b0off + bb;
    int x0 = (tileid & 7) * 32;
    int y0 = (tileid >> 3) * 32;

    const float* wsrc = flat + (size_t)b * TOTAL + 288 + (size_t)ocg * 4 * 288;
    for (int idx = t; idx < 1152; idx += 256) wsm[idx] = wsrc[idx];

    int tx = t & 31;
    int ty4 = (t >> 5) * 4;
    float acc[4][4];
#pragma unroll
    for (int o = 0; o < 4; ++o)
#pragma unroll
        for (int p = 0; p < 4; ++p) acc[o][p] = 0.f;

    const float* inb = out0 + (size_t)bb * 32 * HWHW;
    for (int ic = 0; ic < 32; ++ic) {
        __syncthreads();
        const float* inc = inb + (size_t)ic * HWHW;
        for (int idx = t; idx < 34 * 34; idx += 256) {
            int r = idx / 34, c = idx % 34;
            int gy = y0 - 1 + r, gx = x0 - 1 + c;
            float v = 0.f;
            if (gy >= 0 && gy < HW && gx >= 0 && gx < HW) v = inc[gy * HW + gx];
            tile[idx] = v;
        }
        __syncthreads();
        float xin[6][3];
#pragma unroll
        for (int r = 0; r < 6; ++r)
#pragma unroll
            for (int c = 0; c < 3; ++c) xin[r][c] = tile[(ty4 + r) * 34 + tx + c];
#pragma unroll
        for (int o = 0; o < 4; ++o) {
            float w[9];
#pragma unroll
            for (int k = 0; k < 9; ++k) w[k] = wsm[o * 288 + ic * 9 + k];
#pragma unroll
            for (int p = 0; p < 4; ++p)
#pragma unroll
                for (int ky = 0; ky < 3; ++ky)
#pragma unroll
                    for (int kx = 0; kx < 3; ++kx)
                        acc[o][p] += xin[p + ky][kx] * w[ky * 3 + kx];
        }
    }
#pragma unroll
    for (int o = 0; o < 4; ++o) {
        float* dst = out1 + ((size_t)(bb * 64 + ocg * 4 + o)) * HWHW + (y0 + ty4) * HW + x0 + tx;
#pragma unroll
        for (int p = 0; p < 4; ++p) dst[p * HW] = acc[o][p];
    }
}

// ---------------- conv2: out1[bb,64,H,W] -> out[b,1,H,W]; ker[b,ic] = flat[b, 18720 + ic*9 .. +9] ----------------
__global__ __launch_bounds__(256) void conv2_kernel(
    const float* __restrict__ out1, const float* __restrict__ flat,
    float* __restrict__ out, int b0off)
{
    __shared__ float wsm[576];
    __shared__ float tile[34 * 34];
    int t = threadIdx.x;
    int tileid = blockIdx.x;
    int bb = blockIdx.y;
    int b = b0off + bb;
    int x0 = (tileid & 7) * 32;
    int y0 = (tileid >> 3) * 32;
    const float* wsrc = flat + (size_t)b * TOTAL + 18720;
    for (int idx = t; idx < 576; idx += 256) wsm[idx] = wsrc[idx];
    int tx = t & 31;
    int ty4 = (t >> 5) * 4;
    float acc[4] = {0.f, 0.f, 0.f, 0.f};
    const float* inb = out1 + (size_t)bb * 64 * HWHW;
    for (int ic = 0; ic < 64; ++ic) {
        __syncthreads();
        const float* inc = inb + (size_t)ic * HWHW;
        for (int idx = t; idx < 34 * 34; idx += 256) {
            int r = idx / 34, c = idx % 34;
            int gy = y0 - 1 + r, gx = x0 - 1 + c;
            float v = 0.f;
            if (gy >= 0 && gy < HW && gx >= 0 && gx < HW) v = inc[gy * HW + gx];
            tile[idx] = v;
        }
        __syncthreads();
        float xin[6][3];
#pragma unroll
        for (int r = 0; r < 6; ++r)
#pragma unroll
            for (int c = 0; c < 3; ++c) xin[r][c] = tile[(ty4 + r) * 34 + tx + c];
        float w[9];
#pragma unroll
        for (int k = 0; k < 9; ++k) w[k] = wsm[ic * 9 + k];
#pragma unroll
        for (int p = 0; p < 4; ++p)
#pragma unroll
            for (int ky = 0; ky < 3; ++ky)
#pragma unroll
                for (int kx = 0; kx < 3; ++kx)
                    acc[p] += xin[p + ky][kx] * w[ky * 3 + kx];
    }
    float* dst = out + (size_t)b * HWHW + (y0 + ty4) * HW + x0 + tx;
#pragma unroll
    for (int p = 0; p < 4; ++p) dst[p * HW] = acc[p];
}

extern "C" void kernel_launch(void* const* d_in, const int* in_sizes, int n_in,
                              void* d_out, int out_size, void* d_ws, size_t ws_size,
                              hipStream_t stream)
{
    const float* x_meta = (const float*)d_in[0];
    const float* x      = (const float*)d_in[1];
    const float* w0     = (const float*)d_in[2];
    const float* b0     = (const float*)d_in[3];
    const float* w1     = (const float*)d_in[4];
    const float* b1     = (const float*)d_in[5];
    const float* w2     = (const float*)d_in[6];
    const float* b2     = (const float*)d_in[7];
    float* out = (float*)d_out;

    char* ws = (char*)d_ws;
    float* h1   = (float*)ws;                                  // 16*512 f32 = 32 KB
    float* flat = (float*)(ws + 32768);                        // 16*19296 f32
    size_t flat_bytes = (size_t)16 * TOTAL * sizeof(float);
    size_t fixed = 32768 + ((flat_bytes + 255) & ~(size_t)255);
    size_t per_batch = (size_t)(32 + 64) * HWHW * sizeof(float);  // 24 MB/batch
    int nb = 1;
    if (ws_size > fixed) {
        size_t m = (ws_size - fixed) / per_batch;
        nb = (m >= 16) ? 16 : (m < 1 ? 1 : (int)m);
    }
    float* out0 = (float*)(ws + fixed);
    float* out1 = out0 + (size_t)nb * 32 * HWHW;

    mlp_kernel<<<1, 512, 0, stream>>>(x_meta, w0, b0, w1, b1, h1);
    flat_kernel<<<(TOTAL + 127) / 128, 128, 0, stream>>>(h1, w2, b2, flat);

    for (int B0 = 0; B0 < 16; B0 += nb) {
        int cb = (16 - B0 < nb) ? (16 - B0) : nb;
        conv0_kernel<<<dim3(256, 32, cb), 256, 0, stream>>>(x, flat, out0, B0);
        conv1_kernel<<<dim3(64, 16, cb), 256, 0, stream>>>(out0, flat, out1, B0);
        conv2_kernel<<<dim3(64, cb), 256, 0, stream>>>(out1, flat, out, B0);
    }
}

// Round 2
// 294.973 us; speedup vs baseline: 4.5276x; 4.5276x over previous
//
#include <hip/hip_runtime.h>

#define HW 256
#define HWHW 65536
#define TOTAL 19296

typedef __attribute__((ext_vector_type(8))) short short8;
typedef __attribute__((ext_vector_type(4))) float float4v;

__device__ inline unsigned short f2bf(float f) {
    unsigned u = __builtin_bit_cast(unsigned, f);
    unsigned r = (u + 0x7fff + ((u >> 16) & 1)) >> 16;
    return (unsigned short)r;
}

// ---------------- MLP: one block per batch ----------------
__global__ __launch_bounds__(256) void mlp_kernel(
    const float* __restrict__ x_meta, const float* __restrict__ w0, const float* __restrict__ b0,
    const float* __restrict__ w1, const float* __restrict__ b1, float* __restrict__ h1)
{
    int b = blockIdx.x;
    int t = threadIdx.x;
    __shared__ float xm[16];
    __shared__ float h0s[256];
    if (t < 16) xm[t] = x_meta[b * 16 + t];
    __syncthreads();
    {   // layer1: j = t
        float a0 = b0[t];
#pragma unroll
        for (int i = 0; i < 16; ++i) a0 += xm[i] * w0[i * 256 + t];
        h0s[t] = fmaxf(a0, 0.f);
    }
    __syncthreads();
    {   // layer2: j = t, t+256
        float acc0 = b1[t], acc1 = b1[t + 256];
        for (int k = 0; k < 256; ++k) {
            float hv = h0s[k];  // broadcast
            acc0 += hv * w1[k * 512 + t];
            acc1 += hv * w1[k * 512 + t + 256];
        }
        h1[b * 512 + t] = fmaxf(acc0, 0.f);
        h1[b * 512 + t + 256] = fmaxf(acc1, 0.f);
    }
}

// ---------------- flat2: relu(h1 @ w2 + b2) scattered into weight buffers ----------------
// grid 1206 blocks; block = 16 j x 16 b; each thread computes one (b, j).
__global__ __launch_bounds__(256) void flat2_kernel(
    const float* __restrict__ h1, const float* __restrict__ w2, const float* __restrict__ b2,
    float* __restrict__ wc0, unsigned short* __restrict__ wc1, unsigned short* __restrict__ wc2)
{
    __shared__ float h1s[16 * 512];
    int t = threadIdx.x;
    for (int i = t; i < 2048; i += 256) ((float4*)h1s)[i] = ((const float4*)h1)[i];
    __syncthreads();
    int jj = t & 15, b = t >> 4;
    int j = blockIdx.x * 16 + jj;
    const float* wp = w2 + j;
    const float* hb = h1s + b * 512;
    float acc = 0.f;
    for (int k = 0; k < 512; k += 4) {
        float4 h4 = *(const float4*)&hb[k];
        acc += h4.x * wp[(size_t)(k + 0) * TOTAL];
        acc += h4.y * wp[(size_t)(k + 1) * TOTAL];
        acc += h4.z * wp[(size_t)(k + 2) * TOTAL];
        acc += h4.w * wp[(size_t)(k + 3) * TOTAL];
    }
    float v = fmaxf(acc + b2[j], 0.f);
    if (j < 288) {
        wc0[b * 288 + j] = v;
    } else if (j < 18720) {
        int r = j - 288;
        int oc = r / 288; int rem = r - oc * 288;
        int ic = rem / 9;  int tap = rem - ic * 9;
        wc1[(((b * 9 + tap) * 64 + oc) << 5) + ic] = f2bf(v);
    } else {
        int r = j - 18720;
        int ic = r / 9; int tap = r - ic * 9;
        wc2[(b * 9 + tap) * 64 + ic] = f2bf(v);
    }
}

// ---------------- conv0: x[b,1,H,W] fp32 -> out0[bb][y][x][ic32] bf16 ----------------
__global__ __launch_bounds__(256) void conv0_kernel(
    const float* __restrict__ x, const float* __restrict__ wc0,
    unsigned short* __restrict__ out0, int b0off)
{
    int y = blockIdx.x, bb = blockIdx.y, b = b0off + bb;
    int t = threadIdx.x;
    __shared__ float wsm[288];
    if (t < 288 - 256) wsm[t + 256] = wc0[b * 288 + t + 256];
    wsm[t] = wc0[b * 288 + t];
    __syncthreads();
    const float* xb = x + (size_t)b * HWHW;
    float xv[9];
#pragma unroll
    for (int ky = 0; ky < 3; ++ky) {
        int gy = y + ky - 1;
#pragma unroll
        for (int kx = 0; kx < 3; ++kx) {
            int gx = t + kx - 1;
            float v = 0.f;
            if (gy >= 0 && gy < HW && gx >= 0 && gx < HW) v = xb[gy * HW + gx];
            xv[ky * 3 + kx] = v;
        }
    }
    unsigned pk[16];
#pragma unroll
    for (int op = 0; op < 16; ++op) {
        unsigned short lohi[2];
#pragma unroll
        for (int h = 0; h < 2; ++h) {
            int oc = op * 2 + h;
            float a = 0.f;
#pragma unroll
            for (int k = 0; k < 9; ++k) a += xv[k] * wsm[oc * 9 + k];
            lohi[h] = f2bf(a);
        }
        pk[op] = (unsigned)lohi[0] | ((unsigned)lohi[1] << 16);
    }
    uint4* dst = (uint4*)(out0 + ((size_t)bb * HWHW + y * HW + t) * 32);
#pragma unroll
    for (int i = 0; i < 4; ++i) {
        uint4 q; q.x = pk[i * 4]; q.y = pk[i * 4 + 1]; q.z = pk[i * 4 + 2]; q.w = pk[i * 4 + 3];
        dst[i] = q;
    }
}

// ---------------- conv1: out0 bf16 -> out1[bb][y][x][oc64] bf16, MFMA ----------------
// tile 16x16 px, halo 18x18, LDS px stride 40 shorts (80 B). 4 waves, wave w: rows 4w..4w+3.
#define C1S 40
__global__ __launch_bounds__(256, 3) void conv1_kernel(
    const unsigned short* __restrict__ out0, const unsigned short* __restrict__ wc1,
    unsigned short* __restrict__ out1, int b0off)
{
    __shared__ short tile[324 * C1S];
    int t = threadIdx.x;
    int tid = blockIdx.x, bb = blockIdx.y, b = b0off + bb;
    int x0 = (tid & 15) * 16, y0 = (tid >> 4) * 16;

    // stage 18x18 halo, 64 B per px
    for (int p = t; p < 324; p += 256) {
        int r = p / 18, c = p - r * 18;
        int gy = y0 - 1 + r, gx = x0 - 1 + c;
        uint4 v0 = {0,0,0,0}, v1 = {0,0,0,0}, v2 = {0,0,0,0}, v3 = {0,0,0,0};
        if (gy >= 0 && gy < HW && gx >= 0 && gx < HW) {
            const uint4* src = (const uint4*)(out0 + ((size_t)bb * HWHW + gy * HW + gx) * 32);
            v0 = src[0]; v1 = src[1]; v2 = src[2]; v3 = src[3];
        }
        short* d = tile + p * C1S;
        ((uint4*)d)[0] = v0; ((uint4*)d)[1] = v1; ((uint4*)d)[2] = v2; ((uint4*)d)[3] = v3;
    }
    __syncthreads();

    int lane = t & 63, wave = t >> 6;
    int l15 = lane & 15, lg = lane >> 4;
    float4v acc[4][4];
#pragma unroll
    for (int mt = 0; mt < 4; ++mt)
#pragma unroll
        for (int rr = 0; rr < 4; ++rr) acc[mt][rr] = (float4v){0.f, 0.f, 0.f, 0.f};

    const unsigned short* wb = wc1 + (size_t)(b * 9) * 2048;  // [tap][oc64][ic32]
#pragma unroll
    for (int tap = 0; tap < 9; ++tap) {
        int ky = tap / 3, kx = tap - ky * 3;
        short8 a[4];
#pragma unroll
        for (int mt = 0; mt < 4; ++mt)
            a[mt] = *(const short8*)(wb + tap * 2048 + (mt * 16 + l15) * 32 + lg * 8);
#pragma unroll
        for (int rr = 0; rr < 4; ++rr) {
            int px = (wave * 4 + rr + ky) * 18 + l15 + kx;
            short8 bf = *(const short8*)(tile + px * C1S + lg * 8);
#pragma unroll
            for (int mt = 0; mt < 4; ++mt)
                acc[mt][rr] = __builtin_amdgcn_mfma_f32_16x16x32_bf16(a[mt], bf, acc[mt][rr], 0, 0, 0);
        }
    }

#pragma unroll
    for (int mt = 0; mt < 4; ++mt)
#pragma unroll
        for (int rr = 0; rr < 4; ++rr) {
            int oc = mt * 16 + lg * 4;
            int y = y0 + wave * 4 + rr, xx = x0 + l15;
            float4v a4 = acc[mt][rr];
            unsigned lo = (unsigned)f2bf(a4[0]) | ((unsigned)f2bf(a4[1]) << 16);
            unsigned hi = (unsigned)f2bf(a4[2]) | ((unsigned)f2bf(a4[3]) << 16);
            uint2 pk; pk.x = lo; pk.y = hi;
            *(uint2*)(out1 + ((size_t)bb * HWHW + y * HW + xx) * 64 + oc) = pk;
        }
}

// ---------------- conv2: out1 bf16 -> out fp32, MFMA with M=16 zero-padded (oc=1) ----------------
#define C2S 72
__global__ __launch_bounds__(256, 3) void conv2_kernel(
    const unsigned short* __restrict__ out1, const unsigned short* __restrict__ wc2,
    float* __restrict__ out, int b0off)
{
    __shared__ short tile[324 * C2S];
    int t = threadIdx.x;
    int tid = blockIdx.x, bb = blockIdx.y, b = b0off + bb;
    int x0 = (tid & 15) * 16, y0 = (tid >> 4) * 16;

    for (int p = t; p < 324; p += 256) {
        int r = p / 18, c = p - r * 18;
        int gy = y0 - 1 + r, gx = x0 - 1 + c;
        short* d = tile + p * C2S;
        if (gy >= 0 && gy < HW && gx >= 0 && gx < HW) {
            const uint4* src = (const uint4*)(out1 + ((size_t)bb * HWHW + gy * HW + gx) * 64);
#pragma unroll
            for (int i = 0; i < 8; ++i) ((uint4*)d)[i] = src[i];
        } else {
            uint4 z = {0,0,0,0};
#pragma unroll
            for (int i = 0; i < 8; ++i) ((uint4*)d)[i] = z;
        }
    }
    __syncthreads();

    int lane = t & 63, wave = t >> 6;
    int l15 = lane & 15, lg = lane >> 4;
    const unsigned short* wcb = wc2 + b * 576;  // [tap][ic64]
    short8 a2[9][2];
#pragma unroll
    for (int tap = 0; tap < 9; ++tap)
#pragma unroll
        for (int kc = 0; kc < 2; ++kc) {
            short8 z = {0,0,0,0,0,0,0,0};
            if (l15 == 0) z = *(const short8*)(wcb + tap * 64 + kc * 32 + lg * 8);
            a2[tap][kc] = z;
        }

    float4v acc[4];
#pragma unroll
    for (int rr = 0; rr < 4; ++rr) acc[rr] = (float4v){0.f, 0.f, 0.f, 0.f};
#pragma unroll
    for (int tap = 0; tap < 9; ++tap) {
        int ky = tap / 3, kx = tap - ky * 3;
#pragma unroll
        for (int rr = 0; rr < 4; ++rr) {
            int px = (wave * 4 + rr + ky) * 18 + l15 + kx;
#pragma unroll
            for (int kc = 0; kc < 2; ++kc) {
                short8 bf = *(const short8*)(tile + px * C2S + kc * 32 + lg * 8);
                acc[rr] = __builtin_amdgcn_mfma_f32_16x16x32_bf16(a2[tap][kc], bf, acc[rr], 0, 0, 0);
            }
        }
    }
    if (lane < 16) {
#pragma unroll
        for (int rr = 0; rr < 4; ++rr) {
            int y = y0 + wave * 4 + rr;
            out[(size_t)b * HWHW + y * HW + x0 + lane] = acc[rr][0];
        }
    }
}

extern "C" void kernel_launch(void* const* d_in, const int* in_sizes, int n_in,
                              void* d_out, int out_size, void* d_ws, size_t ws_size,
                              hipStream_t stream)
{
    const float* x_meta = (const float*)d_in[0];
    const float* x      = (const float*)d_in[1];
    const float* w0     = (const float*)d_in[2];
    const float* b0     = (const float*)d_in[3];
    const float* w1     = (const float*)d_in[4];
    const float* b1     = (const float*)d_in[5];
    const float* w2     = (const float*)d_in[6];
    const float* b2     = (const float*)d_in[7];
    float* out = (float*)d_out;

    char* ws = (char*)d_ws;
    float* h1 = (float*)ws;                              // 32 KB
    float* wc0 = (float*)(ws + 32768);                   // 16*288*4 = 18432
    unsigned short* wc1 = (unsigned short*)(ws + 32768 + 18432);          // 16*9*64*32*2 = 589824
    unsigned short* wc2 = (unsigned short*)(ws + 32768 + 18432 + 589824); // 16*9*64*2 = 18432
    size_t fixed = 32768 + 18432 + 589824 + 18432;       // 659456, 256-aligned
    size_t per_batch = (size_t)HWHW * (32 + 64) * 2;     // 12.58 MB
    int nb = 1;
    if (ws_size > fixed) {
        size_t m = (ws_size - fixed) / per_batch;
        nb = (m >= 16) ? 16 : (m < 1 ? 1 : (int)m);
    }
    unsigned short* out0 = (unsigned short*)(ws + fixed);
    unsigned short* out1 = out0 + (size_t)nb * HWHW * 32;

    mlp_kernel<<<16, 256, 0, stream>>>(x_meta, w0, b0, w1, b1, h1);
    flat2_kernel<<<TOTAL / 16, 256, 0, stream>>>(h1, w2, b2, wc0, wc1, wc2);

    for (int B0 = 0; B0 < 16; B0 += nb) {
        int cb = (16 - B0 < nb) ? (16 - B0) : nb;
        conv0_kernel<<<dim3(256, cb), 256, 0, stream>>>(x, wc0, out0, B0);
        conv1_kernel<<<dim3(256, cb), 256, 0, stream>>>(out0, wc1, out1, B0);
        conv2_kernel<<<dim3(256, cb), 256, 0, stream>>>(out1, wc2, out, B0);
    }
}

// Round 3
// 254.535 us; speedup vs baseline: 5.2468x; 1.1589x over previous
//
#include <hip/hip_runtime.h>

#define HW 256
#define HWHW 65536
#define TOTAL 19296

typedef __attribute__((ext_vector_type(8))) short short8;
typedef __attribute__((ext_vector_type(4))) float float4v;

__device__ inline unsigned short f2bf(float f) {
    unsigned u = __builtin_bit_cast(unsigned, f);
    unsigned r = (u + 0x7fff + ((u >> 16) & 1)) >> 16;
    return (unsigned short)r;
}
__device__ inline unsigned pack2(float a, float b) {
    return (unsigned)f2bf(a) | ((unsigned)f2bf(b) << 16);
}

// ---------------- MLP: one block per batch ----------------
__global__ __launch_bounds__(256) void mlp_kernel(
    const float* __restrict__ x_meta, const float* __restrict__ w0, const float* __restrict__ b0,
    const float* __restrict__ w1, const float* __restrict__ b1, float* __restrict__ h1)
{
    int b = blockIdx.x;
    int t = threadIdx.x;
    __shared__ float xm[16];
    __shared__ float h0s[256];
    if (t < 16) xm[t] = x_meta[b * 16 + t];
    __syncthreads();
    {
        float a0 = b0[t];
#pragma unroll
        for (int i = 0; i < 16; ++i) a0 += xm[i] * w0[i * 256 + t];
        h0s[t] = fmaxf(a0, 0.f);
    }
    __syncthreads();
    {
        float acc0 = b1[t], acc1 = b1[t + 256];
        for (int k = 0; k < 256; ++k) {
            float hv = h0s[k];
            acc0 += hv * w1[k * 512 + t];
            acc1 += hv * w1[k * 512 + t + 256];
        }
        h1[b * 512 + t] = fmaxf(acc0, 0.f);
        h1[b * 512 + t + 256] = fmaxf(acc1, 0.f);
    }
}

// ---------------- flat2: relu(h1 @ w2 + b2) scattered into weight buffers ----------------
__global__ __launch_bounds__(256) void flat2_kernel(
    const float* __restrict__ h1, const float* __restrict__ w2, const float* __restrict__ b2,
    float* __restrict__ wc0, unsigned short* __restrict__ wc1, unsigned short* __restrict__ wc2)
{
    __shared__ float h1s[16 * 512];
    int t = threadIdx.x;
    for (int i = t; i < 2048; i += 256) ((float4*)h1s)[i] = ((const float4*)h1)[i];
    __syncthreads();
    int jj = t & 15, b = t >> 4;
    int j = blockIdx.x * 16 + jj;
    const float* wp = w2 + j;
    const float* hb = h1s + b * 512;
    float acc = 0.f;
    for (int k = 0; k < 512; k += 4) {
        float4 h4 = *(const float4*)&hb[k];
        acc += h4.x * wp[(size_t)(k + 0) * TOTAL];
        acc += h4.y * wp[(size_t)(k + 1) * TOTAL];
        acc += h4.z * wp[(size_t)(k + 2) * TOTAL];
        acc += h4.w * wp[(size_t)(k + 3) * TOTAL];
    }
    float v = fmaxf(acc + b2[j], 0.f);
    if (j < 288) {
        wc0[b * 288 + j] = v;
    } else if (j < 18720) {
        int r = j - 288;
        int oc = r / 288; int rem = r - oc * 288;
        int ic = rem / 9;  int tap = rem - ic * 9;
        wc1[(((b * 9 + tap) * 64 + oc) << 5) + ic] = f2bf(v);
    } else {
        int r = j - 18720;
        int ic = r / 9; int tap = r - ic * 9;
        wc2[(b * 9 + tap) * 64 + ic] = f2bf(v);
    }
}

// ---------------- fused conv0+conv1+conv2: one 16x16 output tile per block ----------------
// LDS plan (73472 B total -> 2 blocks/CU):
//   b0s  [400 px][40 sh]  = 32000 B   conv0 out, 20x20 halo, ic32 (+8 pad shorts, 80B stride)
//   b1s  [324 px][64 sh]  = 41472 B   conv1 out, 18x18, oc64, XOR-swizzled 8-short groups
//   xt/w0s overlay b1s (dead before conv1 writes); pbuf [324][12] f32 overlays b1s after conv2 reads.
__global__ __launch_bounds__(256, 2) void fused_conv_kernel(
    const float* __restrict__ x, const float* __restrict__ wc0,
    const unsigned short* __restrict__ wc1, const unsigned short* __restrict__ wc2,
    float* __restrict__ out)
{
    __shared__ __align__(16) char smem[73472];
    short* b0s  = (short*)smem;
    short* b1s  = (short*)(smem + 32000);
    float* xt   = (float*)(smem + 32000);          // 484*4 = 1936 B
    float* w0s  = (float*)(smem + 32000 + 1936);   // 288*4 = 1152 B
    float* pbuf = (float*)(smem + 32000);          // 324*12*4 = 15552 B

    const int t = threadIdx.x;
    const int bx = blockIdx.x, b = blockIdx.y;
    const int x0 = (bx & 15) << 4, y0 = (bx >> 4) << 4;
    const int lane = t & 63, wave = t >> 6;
    const int l15 = lane & 15, lg = lane >> 4;

    // ---- stage xt (22x22 fp32, global rows y0-3..y0+18) + w0s ----
    const float* xb = x + (size_t)b * HWHW;
    for (int i = t; i < 484; i += 256) {
        int r = i / 22, c = i - r * 22;
        int gy = y0 - 3 + r, gx = x0 - 3 + c;
        float v = 0.f;
        if (gy >= 0 && gy < HW && gx >= 0 && gx < HW) v = xb[gy * HW + gx];
        xt[i] = v;
    }
    if (t < 288) w0s[t] = wc0[b * 288 + t];
    else if (t < 288 + 32) { /* nothing */ }
    if (t < 32) w0s[256 + t] = wc0[b * 288 + 256 + t];
    __syncthreads();

    // ---- conv0: 400 px (20x20, global y0-2..y0+17), 32 oc each, scalar VALU ----
    for (int p = t; p < 400; p += 256) {
        int r0 = p / 20, c0 = p - r0 * 20;
        int gy = y0 - 2 + r0, gx = x0 - 2 + c0;
        bool vis = (gy >= 0 && gy < HW && gx >= 0 && gx < HW);
        float xv[9];
#pragma unroll
        for (int ky = 0; ky < 3; ++ky)
#pragma unroll
            for (int kx = 0; kx < 3; ++kx)
                xv[ky * 3 + kx] = xt[(r0 + ky) * 22 + (c0 + kx)];
        uint4* dst = (uint4*)(b0s + p * 40);
#pragma unroll
        for (int q = 0; q < 4; ++q) {
            unsigned pk[4];
#pragma unroll
            for (int h = 0; h < 4; ++h) {
                int oc0 = q * 8 + h * 2;
                float a0 = 0.f, a1 = 0.f;
#pragma unroll
                for (int k = 0; k < 9; ++k) {
                    a0 += xv[k] * w0s[oc0 * 9 + k];
                    a1 += xv[k] * w0s[(oc0 + 1) * 9 + k];
                }
                if (!vis) { a0 = 0.f; a1 = 0.f; }
                pk[h] = pack2(a0, a1);
            }
            uint4 qv; qv.x = pk[0]; qv.y = pk[1]; qv.z = pk[2]; qv.w = pk[3];
            dst[q] = qv;
        }
    }
    __syncthreads();

    // ---- conv1: 21 groups of 16 px over 18x18 (group 20 clamped), MFMA 16x16x32 ----
    // per-wave groups g = wave, wave+4, ...  (wave 0 gets 6, others 5)
    int   p2c[6];
    int   baseb[6];   // byte offset into b0s for B-frag
    bool  inb[6];
#pragma unroll
    for (int i = 0; i < 6; ++i) {
        int g = wave + i * 4;
        if (g < 21) {
            int p2 = g * 16 + l15;
            int pc = p2 > 323 ? 323 : p2;
            p2c[i] = pc;
            int r2 = pc / 18, c2 = pc - r2 * 18;
            baseb[i] = (r2 * 20 + c2) * 80 + lg * 16;
            int gy1 = y0 - 1 + r2, gx1 = x0 - 1 + c2;
            inb[i] = (gy1 >= 0 && gy1 < HW && gx1 >= 0 && gx1 < HW);
        }
    }
    float4v acc1[6][4];
#pragma unroll
    for (int i = 0; i < 6; ++i)
#pragma unroll
        for (int mt = 0; mt < 4; ++mt) acc1[i][mt] = (float4v){0.f, 0.f, 0.f, 0.f};

    const unsigned short* wb = wc1 + (size_t)b * 18432;  // [tap][oc64][ic32]
#pragma unroll
    for (int tap = 0; tap < 9; ++tap) {
        const int ky = tap / 3, kx = tap - (tap / 3) * 3;
        const int toff = (ky * 20 + kx) * 80;  // byte offset in b0s
        short8 A[4];
#pragma unroll
        for (int mt = 0; mt < 4; ++mt)
            A[mt] = *(const short8*)(wb + tap * 2048 + (mt * 16 + l15) * 32 + lg * 8);
#pragma unroll
        for (int i = 0; i < 6; ++i) {
            int g = wave + i * 4;
            if (g < 21) {
                short8 Bf = *(const short8*)((const char*)b0s + baseb[i] + toff);
#pragma unroll
                for (int mt = 0; mt < 4; ++mt)
                    acc1[i][mt] = __builtin_amdgcn_mfma_f32_16x16x32_bf16(A[mt], Bf, acc1[i][mt], 0, 0, 0);
            }
        }
    }
    // C-write into b1s (swizzled), zeroing out-of-image px (SAME-padding for conv2)
#pragma unroll
    for (int i = 0; i < 6; ++i) {
        int g = wave + i * 4;
        if (g < 21) {
#pragma unroll
            for (int mt = 0; mt < 4; ++mt) {
                unsigned lo = pack2(acc1[i][mt][0], acc1[i][mt][1]);
                unsigned hi = pack2(acc1[i][mt][2], acc1[i][mt][3]);
                if (!inb[i]) { lo = 0; hi = 0; }
                int off = mt * 16 + lg * 4;
                int swz = ((off & ~7) ^ ((p2c[i] & 7) * 8)) | (off & 7);
                uint2 pk; pk.x = lo; pk.y = hi;
                *(uint2*)(b1s + p2c[i] * 64 + swz) = pk;
            }
        }
    }

    // conv2 A-frags: A[m=tap][k=ic], rows 9..15 zero
    short8 A2[2];
#pragma unroll
    for (int kc = 0; kc < 2; ++kc) {
        int tp = l15 < 9 ? l15 : 0;
        short8 v = *(const short8*)(wc2 + b * 576 + tp * 64 + kc * 32 + lg * 8);
        short8 z = {0, 0, 0, 0, 0, 0, 0, 0};
        A2[kc] = (l15 < 9) ? v : z;
    }
    __syncthreads();

    // ---- conv2 partials: C[m=tap][n=px] over the 18x18 domain ----
    float4v acc2[6];
#pragma unroll
    for (int i = 0; i < 6; ++i) acc2[i] = (float4v){0.f, 0.f, 0.f, 0.f};
#pragma unroll
    for (int i = 0; i < 6; ++i) {
        int g = wave + i * 4;
        if (g < 21) {
            int pc = p2c[i];
#pragma unroll
            for (int kc = 0; kc < 2; ++kc) {
                int sub = kc * 32 + lg * 8;
                int swz = sub ^ ((pc & 7) * 8);
                short8 Bf = *(const short8*)(b1s + pc * 64 + swz);
                acc2[i] = __builtin_amdgcn_mfma_f32_16x16x32_bf16(A2[kc], Bf, acc2[i], 0, 0, 0);
            }
        }
    }
    __syncthreads();   // all conv2 reads of b1s done; safe to overlay pbuf

#pragma unroll
    for (int i = 0; i < 6; ++i) {
        int g = wave + i * 4;
        if (g < 21) {
            int pc = p2c[i];
            if (lg < 2) {
                *(float4v*)(pbuf + pc * 12 + lg * 4) = acc2[i];
            } else if (lg == 2) {
                pbuf[pc * 12 + 8] = acc2[i][0];
            }
        }
    }
    __syncthreads();

    // ---- reduction: out(r,c) = sum_tap pbuf[(r+ky)*18 + (c+kx)][tap] ----
    {
        int r = t >> 4, c = t & 15;
        float o = 0.f;
#pragma unroll
        for (int ky = 0; ky < 3; ++ky)
#pragma unroll
            for (int kx = 0; kx < 3; ++kx)
                o += pbuf[((r + ky) * 18 + (c + kx)) * 12 + (ky * 3 + kx)];
        out[(size_t)b * HWHW + (y0 + r) * HW + (x0 + c)] = o;
    }
}

extern "C" void kernel_launch(void* const* d_in, const int* in_sizes, int n_in,
                              void* d_out, int out_size, void* d_ws, size_t ws_size,
                              hipStream_t stream)
{
    const float* x_meta = (const float*)d_in[0];
    const float* x      = (const float*)d_in[1];
    const float* w0     = (const float*)d_in[2];
    const float* b0     = (const float*)d_in[3];
    const float* w1     = (const float*)d_in[4];
    const float* b1     = (const float*)d_in[5];
    const float* w2     = (const float*)d_in[6];
    const float* b2     = (const float*)d_in[7];
    float* out = (float*)d_out;

    char* ws = (char*)d_ws;
    float* h1 = (float*)ws;                                                // 32768 B
    float* wc0 = (float*)(ws + 32768);                                     // 18432 B
    unsigned short* wc1 = (unsigned short*)(ws + 32768 + 18432);           // 589824 B
    unsigned short* wc2 = (unsigned short*)(ws + 32768 + 18432 + 589824);  // 18432 B

    mlp_kernel<<<16, 256, 0, stream>>>(x_meta, w0, b0, w1, b1, h1);
    flat2_kernel<<<TOTAL / 16, 256, 0, stream>>>(h1, w2, b2, wc0, wc1, wc2);
    fused_conv_kernel<<<dim3(256, 16), 256, 0, stream>>>(x, wc0, wc1, wc2, out);
}

// Round 4
// 225.366 us; speedup vs baseline: 5.9259x; 1.1294x over previous
//
#include <hip/hip_runtime.h>

#define HW 256
#define HWHW 65536
#define TOTAL 19296

typedef __attribute__((ext_vector_type(8))) short short8;
typedef __attribute__((ext_vector_type(4))) float float4v;

__device__ inline unsigned bfr(float f) {  // bf16 bits (round half-up), low 16
    return (__builtin_bit_cast(unsigned, f) + 0x8000u) >> 16;
}
__device__ inline unsigned pack2rnd(float lo, float hi) {  // [bf(hi):bf(lo)] via v_perm
    unsigned a = __builtin_bit_cast(unsigned, lo) + 0x8000u;
    unsigned b = __builtin_bit_cast(unsigned, hi) + 0x8000u;
    return __builtin_amdgcn_perm(b, a, 0x07060302u);
}

// ---------------- MLP: grid (2 j-halves, 16 b); layer1 recomputed per block ----------------
__global__ __launch_bounds__(256) void mlp_kernel(
    const float* __restrict__ x_meta, const float* __restrict__ w0, const float* __restrict__ b0,
    const float* __restrict__ w1, const float* __restrict__ b1, float* __restrict__ h1)
{
    int b = blockIdx.y, jh = blockIdx.x, t = threadIdx.x;
    __shared__ float xm[16];
    __shared__ float h0s[256];
    if (t < 16) xm[t] = x_meta[b * 16 + t];
    __syncthreads();
    {
        float a0 = b0[t];
#pragma unroll
        for (int i = 0; i < 16; ++i) a0 += xm[i] * w0[i * 256 + t];
        h0s[t] = fmaxf(a0, 0.f);
    }
    __syncthreads();
    int j = jh * 256 + t;
    float acc = b1[j];
#pragma unroll 4
    for (int k = 0; k < 256; ++k) acc += h0s[k] * w1[k * 512 + j];
    h1[b * 512 + j] = fmaxf(acc, 0.f);
}

// ---------------- flat3: split-K partial GEMM. grid (302 j-tiles, 4 k-chunks) ----------------
__global__ __launch_bounds__(256) void flat3_kernel(
    const float* __restrict__ h1, const float* __restrict__ w2, float* __restrict__ part)
{
    __shared__ float h1c[2048];  // [16 b][128 k]
    int t = threadIdx.x;
    int k0 = blockIdx.y * 128;
    for (int i = t; i < 512; i += 256) {
        int b = i >> 5, off = i & 31;
        ((float4*)h1c)[b * 32 + off] = *(const float4*)(h1 + b * 512 + k0 + off * 4);
    }
    __syncthreads();
    int j = blockIdx.x * 64 + (t & 63);
    if (j > TOTAL - 1) j = TOTAL - 1;  // dup writes benign (same value)
    int bq = (t >> 6) * 4;
    const float* hb = h1c + bq * 128;
    float a0 = 0.f, a1 = 0.f, a2 = 0.f, a3 = 0.f;
    for (int k = 0; k < 128; k += 4) {
        float4 h0v = *(const float4*)&hb[k];
        float4 h1v = *(const float4*)&hb[128 + k];
        float4 h2v = *(const float4*)&hb[256 + k];
        float4 h3v = *(const float4*)&hb[384 + k];
#pragma unroll
        for (int u = 0; u < 4; ++u) {
            float wv = w2[(size_t)(k0 + k + u) * TOTAL + j];
            float hu0 = (u == 0) ? h0v.x : (u == 1) ? h0v.y : (u == 2) ? h0v.z : h0v.w;
            float hu1 = (u == 0) ? h1v.x : (u == 1) ? h1v.y : (u == 2) ? h1v.z : h1v.w;
            float hu2 = (u == 0) ? h2v.x : (u == 1) ? h2v.y : (u == 2) ? h2v.z : h2v.w;
            float hu3 = (u == 0) ? h3v.x : (u == 1) ? h3v.y : (u == 2) ? h3v.z : h3v.w;
            a0 += wv * hu0; a1 += wv * hu1; a2 += wv * hu2; a3 += wv * hu3;
        }
    }
    float* pp = part + (size_t)(blockIdx.y * 16 + bq) * TOTAL + j;
    pp[0] = a0; pp[(size_t)TOTAL] = a1; pp[(size_t)2 * TOTAL] = a2; pp[(size_t)3 * TOTAL] = a3;
}

// ---------------- flatfin: reduce 4 partials + bias + relu, scatter to weight buffers ----------------
__global__ __launch_bounds__(256) void flatfin_kernel(
    const float* __restrict__ part, const float* __restrict__ b2,
    float* __restrict__ wc0, unsigned short* __restrict__ wc1, unsigned short* __restrict__ wc2)
{
    int j = blockIdx.x * 256 + threadIdx.x;
    int b = blockIdx.y;
    if (j >= TOTAL) return;
    float s = 0.f;
#pragma unroll
    for (int ky = 0; ky < 4; ++ky) s += part[(size_t)(ky * 16 + b) * TOTAL + j];
    float v = fmaxf(s + b2[j], 0.f);
    if (j < 288) {
        wc0[b * 288 + j] = v;
    } else if (j < 18720) {
        int r = j - 288;
        int oc = r / 288; int rem = r - oc * 288;
        int ic = rem / 9;  int tap = rem - ic * 9;
        wc1[(((b * 9 + tap) * 64 + oc) << 5) + ic] = (unsigned short)bfr(v);
    } else {
        int r = j - 18720;
        int ic = r / 9; int tap = r - ic * 9;
        wc2[(b * 9 + tap) * 64 + ic] = (unsigned short)bfr(v);
    }
}

// ---------------- fused conv0+conv1+conv2: one 16x16 output tile per block ----------------
// LDS (73472 B -> 2 blocks/CU):
//   b0s  [400 px][40 sh] = 32000 B   conv0 out, 20x20 halo, ic32 (80 B px stride)
//   b1s  [324 px][64 sh] = 41472 B   conv1 out, 18x18, oc64, XOR-swizzled 8-short groups
//   xt/w0s overlay b1s (dead before conv1 epilogue); pbuf [324][13] f32 overlays b1s after conv2 reads.
__global__ __launch_bounds__(256, 2) void fused_conv_kernel(
    const float* __restrict__ x, const float* __restrict__ wc0,
    const unsigned short* __restrict__ wc1, const unsigned short* __restrict__ wc2,
    float* __restrict__ out)
{
    __shared__ __align__(16) char smem[73472];
    short* b0s  = (short*)smem;
    short* b1s  = (short*)(smem + 32000);
    float* xt   = (float*)(smem + 32000);          // 484*4 = 1936 B
    float* w0s  = (float*)(smem + 32000 + 1936);   // 288*4 = 1152 B
    float* pbuf = (float*)(smem + 32000);          // 324*13*4 = 16848 B

    const int t = threadIdx.x;
    const int bx = blockIdx.x, b = blockIdx.y;
    const int x0 = (bx & 15) << 4, y0 = (bx >> 4) << 4;
    const int lane = t & 63, wave = t >> 6;
    const int l15 = lane & 15, lg = lane >> 4;

    // ---- stage xt (22x22 fp32 from y0-3,x0-3) + w0s ----
    const float* xb = x + (size_t)b * HWHW;
    for (int i = t; i < 484; i += 256) {
        int r = i / 22, c = i - r * 22;
        int gy = y0 - 3 + r, gx = x0 - 3 + c;
        float v = 0.f;
        if (gy >= 0 && gy < HW && gx >= 0 && gx < HW) v = xb[gy * HW + gx];
        xt[i] = v;
    }
    if (t < 288) w0s[t] = wc0[b * 288 + t];
    if (t < 32)  w0s[256 + t] = wc0[b * 288 + 256 + t];
    __syncthreads();

    // ---- conv0 via MFMA: M=32 oc, K=taps(9, zero-pad 32), N=400 px in 25 groups ----
    short8 A0, A1;
    {
        short8 z = {0,0,0,0,0,0,0,0};
        A0 = z; A1 = z;
#pragma unroll
        for (int mt = 0; mt < 2; ++mt) {
            const float* wp = w0s + (mt * 16 + l15) * 9;
            short8 a = z;
            if (lg == 0) {
                uint4 pk;
                pk.x = pack2rnd(wp[0], wp[1]);
                pk.y = pack2rnd(wp[2], wp[3]);
                pk.z = pack2rnd(wp[4], wp[5]);
                pk.w = pack2rnd(wp[6], wp[7]);
                a = __builtin_bit_cast(short8, pk);
            } else if (lg == 1) {
                a[0] = (short)bfr(wp[8]);
            }
            if (mt == 0) A0 = a; else A1 = a;
        }
    }
    for (int g = wave; g < 25; g += 4) {
        int px = g * 16 + l15;                 // 0..399
        int r0 = px / 20, c0 = px - r0 * 20;
        int gy = y0 - 2 + r0, gx = x0 - 2 + c0;
        bool vis = (gy >= 0 && gy < HW && gx >= 0 && gx < HW);
        short8 Bf = {0,0,0,0,0,0,0,0};
        const float* xp = xt + r0 * 22 + c0;
        if (lg == 0) {
            uint4 pk;
            pk.x = pack2rnd(xp[0],  xp[1]);
            pk.y = pack2rnd(xp[2],  xp[22]);
            pk.z = pack2rnd(xp[23], xp[24]);
            pk.w = pack2rnd(xp[44], xp[45]);
            Bf = __builtin_bit_cast(short8, pk);
        } else if (lg == 1) {
            Bf[0] = (short)bfr(xp[46]);
        }
        float4v zz = {0.f, 0.f, 0.f, 0.f};
        float4v d0 = __builtin_amdgcn_mfma_f32_16x16x32_bf16(A0, Bf, zz, 0, 0, 0);
        float4v d1 = __builtin_amdgcn_mfma_f32_16x16x32_bf16(A1, Bf, zz, 0, 0, 0);
        uint2 wv0, wv1;
        wv0.x = pack2rnd(d0[0], d0[1]); wv0.y = pack2rnd(d0[2], d0[3]);
        wv1.x = pack2rnd(d1[0], d1[1]); wv1.y = pack2rnd(d1[2], d1[3]);
        if (!vis) { wv0.x = 0; wv0.y = 0; wv1.x = 0; wv1.y = 0; }
        *(uint2*)(b0s + px * 40 + lg * 4)      = wv0;
        *(uint2*)(b0s + px * 40 + 16 + lg * 4) = wv1;
    }
    __syncthreads();

    // ---- conv1: 21 groups of 16 px over 18x18, MFMA 16x16x32, acc-resident ----
    int  p2c[6];
    int  baseb[6];
    bool inb[6];
#pragma unroll
    for (int i = 0; i < 6; ++i) {
        int g = wave + i * 4;
        if (g < 21) {
            int p2 = g * 16 + l15;
            int pc = p2 > 323 ? 323 : p2;
            p2c[i] = pc;
            int r2 = pc / 18, c2 = pc - r2 * 18;
            baseb[i] = (r2 * 20 + c2) * 80 + lg * 16;
            int gy1 = y0 - 1 + r2, gx1 = x0 - 1 + c2;
            inb[i] = (gy1 >= 0 && gy1 < HW && gx1 >= 0 && gx1 < HW);
        }
    }
    float4v acc1[6][4];
#pragma unroll
    for (int i = 0; i < 6; ++i)
#pragma unroll
        for (int mt = 0; mt < 4; ++mt) acc1[i][mt] = (float4v){0.f, 0.f, 0.f, 0.f};

    const unsigned short* wb = wc1 + (size_t)b * 18432;  // [tap][oc64][ic32]
#pragma unroll
    for (int tap = 0; tap < 9; ++tap) {
        const int ky = tap / 3, kx = tap - (tap / 3) * 3;
        const int toff = (ky * 20 + kx) * 80;
        short8 A[4];
#pragma unroll
        for (int mt = 0; mt < 4; ++mt)
            A[mt] = *(const short8*)(wb + tap * 2048 + (mt * 16 + l15) * 32 + lg * 8);
#pragma unroll
        for (int i = 0; i < 6; ++i) {
            int g = wave + i * 4;
            if (g < 21) {
                short8 Bf = *(const short8*)((const char*)b0s + baseb[i] + toff);
#pragma unroll
                for (int mt = 0; mt < 4; ++mt)
                    acc1[i][mt] = __builtin_amdgcn_mfma_f32_16x16x32_bf16(A[mt], Bf, acc1[i][mt], 0, 0, 0);
            }
        }
    }
    // conv2 A-frags (global, overlap with epilogue): A[m=tap][k=ic], rows 9..15 zero
    short8 A2[2];
#pragma unroll
    for (int kc = 0; kc < 2; ++kc) {
        int tp = l15 < 9 ? l15 : 0;
        short8 v = *(const short8*)(wc2 + b * 576 + tp * 64 + kc * 32 + lg * 8);
        short8 z = {0, 0, 0, 0, 0, 0, 0, 0};
        A2[kc] = (l15 < 9) ? v : z;
    }
    // C-write into b1s (XOR-swizzled), zeroing out-of-image px
#pragma unroll
    for (int i = 0; i < 6; ++i) {
        int g = wave + i * 4;
        if (g < 21) {
#pragma unroll
            for (int mt = 0; mt < 4; ++mt) {
                unsigned lo = pack2rnd(acc1[i][mt][0], acc1[i][mt][1]);
                unsigned hi = pack2rnd(acc1[i][mt][2], acc1[i][mt][3]);
                if (!inb[i]) { lo = 0; hi = 0; }
                int off = mt * 16 + lg * 4;
                int swz = ((off & ~7) ^ ((p2c[i] & 7) * 8)) | (off & 7);
                uint2 pk; pk.x = lo; pk.y = hi;
                *(uint2*)(b1s + p2c[i] * 64 + swz) = pk;
            }
        }
    }
    __syncthreads();

    // ---- conv2 partials: C[m=tap][n=px] over 18x18 ----
    float4v acc2[6];
#pragma unroll
    for (int i = 0; i < 6; ++i) acc2[i] = (float4v){0.f, 0.f, 0.f, 0.f};
#pragma unroll
    for (int i = 0; i < 6; ++i) {
        int g = wave + i * 4;
        if (g < 21) {
            int pc = p2c[i];
#pragma unroll
            for (int kc = 0; kc < 2; ++kc) {
                int sub = kc * 32 + lg * 8;
                int swz = sub ^ ((pc & 7) * 8);
                short8 Bf = *(const short8*)(b1s + pc * 64 + swz);
                acc2[i] = __builtin_amdgcn_mfma_f32_16x16x32_bf16(A2[kc], Bf, acc2[i], 0, 0, 0);
            }
        }
    }
    __syncthreads();   // b1s reads done; overlay pbuf

#pragma unroll
    for (int i = 0; i < 6; ++i) {
        int g = wave + i * 4;
        if (g < 21) {
            int pc = p2c[i];
            if (lg < 2) {
#pragma unroll
                for (int u = 0; u < 4; ++u) pbuf[pc * 13 + lg * 4 + u] = acc2[i][u];
            } else if (lg == 2) {
                pbuf[pc * 13 + 8] = acc2[i][0];
            }
        }
    }
    __syncthreads();

    // ---- reduction: out(r,c) = sum_tap pbuf[(r+ky)*18 + (c+kx)][tap] ----
    {
        int r = t >> 4, c = t & 15;
        float o = 0.f;
#pragma unroll
        for (int ky = 0; ky < 3; ++ky)
#pragma unroll
            for (int kx = 0; kx < 3; ++kx)
                o += pbuf[((r + ky) * 18 + (c + kx)) * 13 + (ky * 3 + kx)];
        out[(size_t)b * HWHW + (y0 + r) * HW + (x0 + c)] = o;
    }
}

extern "C" void kernel_launch(void* const* d_in, const int* in_sizes, int n_in,
                              void* d_out, int out_size, void* d_ws, size_t ws_size,
                              hipStream_t stream)
{
    const float* x_meta = (const float*)d_in[0];
    const float* x      = (const float*)d_in[1];
    const float* w0     = (const float*)d_in[2];
    const float* b0     = (const float*)d_in[3];
    const float* w1     = (const float*)d_in[4];
    const float* b1     = (const float*)d_in[5];
    const float* w2     = (const float*)d_in[6];
    const float* b2     = (const float*)d_in[7];
    float* out = (float*)d_out;

    char* ws = (char*)d_ws;
    float* h1 = (float*)ws;                                                // @0       32768 B
    float* wc0 = (float*)(ws + 32768);                                     // @32768   18432 B
    unsigned short* wc1 = (unsigned short*)(ws + 51200);                   // @51200   589824 B
    unsigned short* wc2 = (unsigned short*)(ws + 641024);                  // @641024  18432 B
    float* part = (float*)(ws + 659456);                                   // @659456  4939776 B

    mlp_kernel<<<dim3(2, 16), 256, 0, stream>>>(x_meta, w0, b0, w1, b1, h1);
    flat3_kernel<<<dim3(302, 4), 256, 0, stream>>>(h1, w2, part);
    flatfin_kernel<<<dim3(76, 16), 256, 0, stream>>>(part, b2, wc0, wc1, wc2);
    fused_conv_kernel<<<dim3(256, 16), 256, 0, stream>>>(x, wc0, wc1, wc2, out);
}